// Round 8
// baseline (274.318 us; speedup 1.0000x reference)
//
#include <hip/hip_runtime.h>

#define N_NODES 50000
#define N_EDGES 800000
#define H 64
#define NBLK 196        // ceil(50000/256)
#define TOTAL_WAVES 8192
#define NPWMAX 7        // ceil(50000/8192)

typedef float floatx4 __attribute__((ext_vector_type(4)));

__device__ __forceinline__ float readlane_f(float x, int i) {
    return __int_as_float(__builtin_amdgcn_readlane(__float_as_int(x), i));
}

// ---- Stage 1: histogram of receiver counts (4 edges/thread, int4 loads) ----
__global__ __launch_bounds__(256) void hist_kernel(
    const int* __restrict__ recv, unsigned* __restrict__ counts)
{
    int i = blockIdx.x * 256 + threadIdx.x;
    if (i < N_EDGES / 4) {
        int4 r = reinterpret_cast<const int4*>(recv)[i];
        atomicAdd(&counts[r.x], 1u);
        atomicAdd(&counts[r.y], 1u);
        atomicAdd(&counts[r.z], 1u);
        atomicAdd(&counts[r.w], 1u);
    }
}

// ---- Stage 2a: per-block reduce of counts ----
__global__ __launch_bounds__(256) void scanA_kernel(
    const unsigned* __restrict__ counts, unsigned* __restrict__ blockSums)
{
    __shared__ unsigned red[256];
    int i = blockIdx.x * 256 + threadIdx.x;
    unsigned s = (i < N_NODES) ? counts[i] : 0u;
    red[threadIdx.x] = s;
    __syncthreads();
    for (int off = 128; off > 0; off >>= 1) {
        if (threadIdx.x < off) red[threadIdx.x] += red[threadIdx.x + off];
        __syncthreads();
    }
    if (threadIdx.x == 0) blockSums[blockIdx.x] = red[0];
}

// ---- Stage 2b: per-block scan; each block derives its own prefix from blockSums ----
__global__ __launch_bounds__(256) void scanC_kernel(
    const unsigned* __restrict__ counts, const unsigned* __restrict__ blockSums,
    unsigned* __restrict__ offsets, unsigned* __restrict__ cursor)
{
    __shared__ unsigned sh[256];
    const int t = threadIdx.x;

    sh[t] = (t < blockIdx.x && t < NBLK) ? blockSums[t] : 0u;
    __syncthreads();
    for (int off = 128; off > 0; off >>= 1) {
        if (t < off) sh[t] += sh[t + off];
        __syncthreads();
    }
    unsigned blockPrefix = sh[0];
    __syncthreads();

    int i = blockIdx.x * 256 + t;
    unsigned c = (i < N_NODES) ? counts[i] : 0u;
    sh[t] = c;
    __syncthreads();
    for (int off = 1; off < 256; off <<= 1) {
        unsigned vv = (t >= off) ? sh[t - off] : 0u;
        __syncthreads();
        sh[t] += vv;
        __syncthreads();
    }
    unsigned ex = sh[t] - c + blockPrefix;
    if (i < N_NODES) { offsets[i] = ex; cursor[i] = ex; }
    if (i == 0) offsets[N_NODES] = N_EDGES;
}

// ---- Stage 3a: per-edge destination slot (sorted position) ----
__global__ __launch_bounds__(256) void dst_kernel(
    const int* __restrict__ recv, unsigned* __restrict__ cursor,
    unsigned* __restrict__ dst)
{
    int i = blockIdx.x * 256 + threadIdx.x;
    if (i < N_EDGES / 4) {
        int4 r = reinterpret_cast<const int4*>(recv)[i];
        uint4 d;
        d.x = atomicAdd(&cursor[r.x], 1u);
        d.y = atomicAdd(&cursor[r.y], 1u);
        d.z = atomicAdd(&cursor[r.z], 1u);
        d.w = atomicAdd(&cursor[r.w], 1u);
        reinterpret_cast<uint4*>(dst)[i] = d;
    }
}

// ---- Stage 3b (fallback path): scatter edge IDs into buckets ----
__global__ __launch_bounds__(256) void bucket_kernel(
    const int* __restrict__ recv, unsigned* __restrict__ cursor,
    unsigned* __restrict__ perm)
{
    int i = blockIdx.x * 256 + threadIdx.x;
    if (i < N_EDGES / 4) {
        int4 r = reinterpret_cast<const int4*>(recv)[i];
        unsigned p0 = atomicAdd(&cursor[r.x], 1u);
        unsigned p1 = atomicAdd(&cursor[r.y], 1u);
        unsigned p2 = atomicAdd(&cursor[r.z], 1u);
        unsigned p3 = atomicAdd(&cursor[r.w], 1u);
        perm[p0] = (unsigned)(i * 4 + 0);
        perm[p1] = (unsigned)(i * 4 + 1);
        perm[p2] = (unsigned)(i * 4 + 2);
        perm[p3] = (unsigned)(i * 4 + 3);
    }
}

// ---- Stage 4: permuted copy. Sequential read of E, scattered 256B-row writes ----
__global__ __launch_bounds__(256) void copy_kernel(
    const float* __restrict__ E, const unsigned* __restrict__ dst,
    float* __restrict__ Es)
{
    int t = blockIdx.x * 256 + threadIdx.x;   // t < N_EDGES*16
    int edge = t >> 4;
    int c = t & 15;
    unsigned pos = dst[edge];
    const floatx4* E4 = reinterpret_cast<const floatx4*>(E);
    floatx4* Es4 = reinterpret_cast<floatx4*>(Es);
    floatx4 val = __builtin_nontemporal_load(E4 + (size_t)edge * 16 + c);
    __builtin_nontemporal_store(val, Es4 + (size_t)pos * 16 + c);
}

// ---- Stage 5: fused segmented mean (contiguous rows) + 3-layer MLP ----
// 16 waves/block, one node/wave. Lane l: row-group g=l>>4, chunk c=l&15.
// Rows for node n are contiguous [beg,end) in Es -> streaming 1KB wave-loads.
__global__ __launch_bounds__(1024, 2) void gather_mlp_kernel(
    const float* __restrict__ Es, const unsigned* __restrict__ offsets,
    const float* __restrict__ v,
    const float* __restrict__ W0, const float* __restrict__ b0,
    const float* __restrict__ W1, const float* __restrict__ b1,
    const float* __restrict__ W2, const float* __restrict__ b2,
    float* __restrict__ out)
{
    __shared__ float sW0[128 * 64];
    __shared__ float sW1[64 * 64];
    __shared__ float sW2[64 * 64];
    __shared__ float sB[3 * 64];

    for (int i = threadIdx.x; i < 128 * 64; i += 1024) sW0[i] = W0[i];
    for (int i = threadIdx.x; i < 64 * 64; i += 1024) sW1[i] = W1[i];
    for (int i = threadIdx.x; i < 64 * 64; i += 1024) sW2[i] = W2[i];
    if (threadIdx.x < 192) {
        sB[threadIdx.x] = (threadIdx.x < 64)   ? b0[threadIdx.x]
                        : (threadIdx.x < 128)  ? b1[threadIdx.x - 64]
                                               : b2[threadIdx.x - 128];
    }
    __syncthreads();

    const int lane = threadIdx.x & 63;
    int n = blockIdx.x * 16 + (threadIdx.x >> 6);    // 3125 * 16 = 50000 exactly
    n = __builtin_amdgcn_readfirstlane(n);

    int beg = __builtin_amdgcn_readfirstlane((int)offsets[n]);
    int end = __builtin_amdgcn_readfirstlane((int)offsets[n + 1]);
    int cnt = end - beg;

    const int g = lane >> 4;
    const int c = lane & 15;
    const floatx4* Es4 = reinterpret_cast<const floatx4*>(Es);

    floatx4 accA = (floatx4)0.0f;
    floatx4 accB = (floatx4)0.0f;
    for (int p = beg; p < end; p += 8) {
        int rA = p + g;
        int rB = p + 4 + g;
        if (rA < end) accA += __builtin_nontemporal_load(Es4 + (size_t)rA * 16 + c);
        if (rB < end) accB += __builtin_nontemporal_load(Es4 + (size_t)rB * 16 + c);
    }
    float sx = accA.x + accB.x;
    float sy = accA.y + accB.y;
    float sz = accA.z + accB.z;
    float sw = accA.w + accB.w;

    // reduce across the 4 row-groups (lane bits 4,5) -> all lanes hold sums for chunk c
    sx += __shfl_xor(sx, 16); sy += __shfl_xor(sy, 16);
    sz += __shfl_xor(sz, 16); sw += __shfl_xor(sw, 16);
    sx += __shfl_xor(sx, 32); sy += __shfl_xor(sy, 32);
    sz += __shfl_xor(sz, 32); sw += __shfl_xor(sw, 32);

    float invc = (cnt > 0) ? 1.0f / (float)cnt : 0.0f;

    // redistribute: feature f=lane lives in source lane f>>2, component f&3
    int srcLane = lane >> 2;
    float t0 = __shfl(sx, srcLane);
    float t1 = __shfl(sy, srcLane);
    float t2 = __shfl(sz, srcLane);
    float t3 = __shfl(sw, srcLane);
    float xa = (lane & 2) ? ((lane & 1) ? t3 : t2)
                          : ((lane & 1) ? t1 : t0);
    xa *= invc;

    float xv = v[(size_t)n * H + lane];

    // ---- MLP: lane j = output feature j ----
    float acc = sB[lane];
    #pragma unroll 16
    for (int i = 0; i < 64; ++i)
        acc = fmaf(readlane_f(xa, i), sW0[i * 64 + lane], acc);
    #pragma unroll 16
    for (int i = 0; i < 64; ++i)
        acc = fmaf(readlane_f(xv, i), sW0[(64 + i) * 64 + lane], acc);
    float y = fmaxf(acc, 0.0f);

    acc = sB[64 + lane];
    #pragma unroll 16
    for (int i = 0; i < 64; ++i)
        acc = fmaf(readlane_f(y, i), sW1[i * 64 + lane], acc);
    float z = fmaxf(acc, 0.0f);

    acc = sB[128 + lane];
    #pragma unroll 16
    for (int i = 0; i < 64; ++i)
        acc = fmaf(readlane_f(z, i), sW2[i * 64 + lane], acc);

    out[(size_t)n * H + lane] = acc;
}

// ---- Fallback (small ws): R5 fused perm-gather + MLP ----
__global__ __launch_bounds__(1024, 8) void gather_mlp_perm_kernel(
    const float* __restrict__ E, const unsigned* __restrict__ offsets,
    const unsigned* __restrict__ perm, const float* __restrict__ v,
    const float* __restrict__ W0, const float* __restrict__ b0,
    const float* __restrict__ W1, const float* __restrict__ b1,
    const float* __restrict__ W2, const float* __restrict__ b2,
    float* __restrict__ out)
{
    __shared__ float sW0[128 * 64];
    __shared__ float sW1[64 * 64];
    __shared__ float sW2[64 * 64];
    __shared__ float sB[3 * 64];

    for (int i = threadIdx.x; i < 128 * 64; i += 1024) sW0[i] = W0[i];
    for (int i = threadIdx.x; i < 64 * 64; i += 1024) sW1[i] = W1[i];
    for (int i = threadIdx.x; i < 64 * 64; i += 1024) sW2[i] = W2[i];
    if (threadIdx.x < 192) {
        sB[threadIdx.x] = (threadIdx.x < 64)   ? b0[threadIdx.x]
                        : (threadIdx.x < 128)  ? b1[threadIdx.x - 64]
                                               : b2[threadIdx.x - 128];
    }
    __syncthreads();

    const int lane = threadIdx.x & 63;
    int gg = (blockIdx.x * 1024 + threadIdx.x) >> 6;
    gg = __builtin_amdgcn_readfirstlane(gg);

    float xa[NPWMAX], xv[NPWMAX];
    #pragma unroll
    for (int j = 0; j < NPWMAX; ++j) {
        int n = gg + j * TOTAL_WAVES;
        xa[j] = 0.0f; xv[j] = 0.0f;
        if (n < N_NODES) {
            xv[j] = v[(size_t)n * H + lane];
            int beg = __builtin_amdgcn_readfirstlane((int)offsets[n]);
            int end = __builtin_amdgcn_readfirstlane((int)offsets[n + 1]);
            int cnt = end - beg;
            float a0 = 0.f, a1 = 0.f, a2 = 0.f, a3 = 0.f;
            int p = beg;
            for (; p + 3 < end; p += 4) {
                int e0 = (int)perm[p];
                int e1 = (int)perm[p + 1];
                int e2 = (int)perm[p + 2];
                int e3 = (int)perm[p + 3];
                a0 += E[(size_t)e0 * H + lane];
                a1 += E[(size_t)e1 * H + lane];
                a2 += E[(size_t)e2 * H + lane];
                a3 += E[(size_t)e3 * H + lane];
            }
            for (; p < end; ++p) a0 += E[(size_t)perm[p] * H + lane];
            float invc = (cnt > 0) ? 1.0f / (float)cnt : 0.0f;
            xa[j] = (a0 + a1 + a2 + a3) * invc;
        }
    }

    float acc[NPWMAX];
    #pragma unroll
    for (int j = 0; j < NPWMAX; ++j) acc[j] = sB[lane];
    #pragma unroll 8
    for (int i = 0; i < 64; ++i) {
        float w = sW0[i * 64 + lane];
        #pragma unroll
        for (int j = 0; j < NPWMAX; ++j) acc[j] = fmaf(readlane_f(xa[j], i), w, acc[j]);
    }
    #pragma unroll 8
    for (int i = 0; i < 64; ++i) {
        float w = sW0[(64 + i) * 64 + lane];
        #pragma unroll
        for (int j = 0; j < NPWMAX; ++j) acc[j] = fmaf(readlane_f(xv[j], i), w, acc[j]);
    }
    float y[NPWMAX];
    #pragma unroll
    for (int j = 0; j < NPWMAX; ++j) y[j] = fmaxf(acc[j], 0.0f);

    #pragma unroll
    for (int j = 0; j < NPWMAX; ++j) acc[j] = sB[64 + lane];
    #pragma unroll 8
    for (int i = 0; i < 64; ++i) {
        float w = sW1[i * 64 + lane];
        #pragma unroll
        for (int j = 0; j < NPWMAX; ++j) acc[j] = fmaf(readlane_f(y[j], i), w, acc[j]);
    }
    float z[NPWMAX];
    #pragma unroll
    for (int j = 0; j < NPWMAX; ++j) z[j] = fmaxf(acc[j], 0.0f);

    #pragma unroll
    for (int j = 0; j < NPWMAX; ++j) acc[j] = sB[128 + lane];
    #pragma unroll 8
    for (int i = 0; i < 64; ++i) {
        float w = sW2[i * 64 + lane];
        #pragma unroll
        for (int j = 0; j < NPWMAX; ++j) acc[j] = fmaf(readlane_f(z[j], i), w, acc[j]);
    }

    #pragma unroll
    for (int j = 0; j < NPWMAX; ++j) {
        int n = gg + j * TOTAL_WAVES;
        if (n < N_NODES) out[(size_t)n * H + lane] = acc[j];
    }
}

extern "C" void kernel_launch(void* const* d_in, const int* in_sizes, int n_in,
                              void* d_out, int out_size, void* d_ws, size_t ws_size,
                              hipStream_t stream)
{
    const float* v  = (const float*)d_in[0];
    const int*   ei = (const int*)d_in[1];     // [2, 800000]; row 1 = receiver
    const float* e  = (const float*)d_in[2];
    const float* W0 = (const float*)d_in[3];
    const float* b0 = (const float*)d_in[4];
    const float* W1 = (const float*)d_in[5];
    const float* b1 = (const float*)d_in[6];
    const float* W2 = (const float*)d_in[7];
    const float* b2 = (const float*)d_in[8];
    float* out = (float*)d_out;

    // workspace layout (u32 elements)
    unsigned* W = (unsigned*)d_ws;
    unsigned* counts    = W;                  // [0, 50176)
    unsigned* offsets   = W + 50176;          // 50001 (+pad) -> [50176, 100352)
    unsigned* cursor    = W + 100352;         // 50000 (+pad) -> [100352, 150528)
    unsigned* blockSums = W + 150528;         // 196 (+pad)   -> [150528, 150784)
    unsigned* dst       = W + 150784;         // 800000       -> [150784, 950784)
    float*    Es        = (float*)(W + 950784); // 51.2M floats (204.8 MB)
    const int* recv = ei + N_EDGES;

    const size_t wsNeed = (size_t)(950784 + 51200000) * 4;

    (void)hipMemsetAsync(counts, 0, 50176 * sizeof(unsigned), stream);

    hist_kernel<<<(N_EDGES / 4 + 255) / 256, 256, 0, stream>>>(recv, counts);
    scanA_kernel<<<NBLK, 256, 0, stream>>>(counts, blockSums);
    scanC_kernel<<<NBLK, 256, 0, stream>>>(counts, blockSums, offsets, cursor);

    if (ws_size >= wsNeed) {
        dst_kernel<<<(N_EDGES / 4 + 255) / 256, 256, 0, stream>>>(recv, cursor, dst);
        copy_kernel<<<(N_EDGES * 16) / 256, 256, 0, stream>>>(e, dst, Es);
        gather_mlp_kernel<<<N_NODES / 16, 1024, 0, stream>>>(
            Es, offsets, v, W0, b0, W1, b1, W2, b2, out);
    } else {
        unsigned* perm = dst;  // reuse slot
        bucket_kernel<<<(N_EDGES / 4 + 255) / 256, 256, 0, stream>>>(recv, cursor, perm);
        gather_mlp_perm_kernel<<<512, 1024, 0, stream>>>(
            e, offsets, perm, v, W0, b0, W1, b1, W2, b2, out);
    }
}

// Round 9
// 231.128 us; speedup vs baseline: 1.1869x; 1.1869x over previous
//
#include <hip/hip_runtime.h>

#define N_NODES 50000
#define N_EDGES 800000
#define H 64
#define NBLK 196        // ceil(50000/256)
#define TOTAL_WAVES 8192
#define NPWMAX 7        // ceil(50000/8192)

typedef float floatx4 __attribute__((ext_vector_type(4)));

__device__ __forceinline__ float readlane_f(float x, int i) {
    return __int_as_float(__builtin_amdgcn_readlane(__float_as_int(x), i));
}
__device__ __forceinline__ unsigned bf16rne(float x) {
    unsigned u = __float_as_uint(x);
    return (u + 0x7FFFu + ((u >> 16) & 1u)) >> 16;
}
__device__ __forceinline__ float bf16lo(unsigned u) { return __uint_as_float(u << 16); }
__device__ __forceinline__ float bf16hi(unsigned u) { return __uint_as_float(u & 0xFFFF0000u); }

// ---- Stage 1: histogram of receiver counts ----
__global__ __launch_bounds__(256) void hist_kernel(
    const int* __restrict__ recv, unsigned* __restrict__ counts)
{
    int i = blockIdx.x * 256 + threadIdx.x;
    if (i < N_EDGES / 4) {
        int4 r = reinterpret_cast<const int4*>(recv)[i];
        atomicAdd(&counts[r.x], 1u);
        atomicAdd(&counts[r.y], 1u);
        atomicAdd(&counts[r.z], 1u);
        atomicAdd(&counts[r.w], 1u);
    }
}

// ---- Stage 2a: per-block reduce ----
__global__ __launch_bounds__(256) void scanA_kernel(
    const unsigned* __restrict__ counts, unsigned* __restrict__ blockSums)
{
    __shared__ unsigned red[256];
    int i = blockIdx.x * 256 + threadIdx.x;
    unsigned s = (i < N_NODES) ? counts[i] : 0u;
    red[threadIdx.x] = s;
    __syncthreads();
    for (int off = 128; off > 0; off >>= 1) {
        if (threadIdx.x < off) red[threadIdx.x] += red[threadIdx.x + off];
        __syncthreads();
    }
    if (threadIdx.x == 0) blockSums[blockIdx.x] = red[0];
}

// ---- Stage 2b: per-block scan (derives own prefix) ----
__global__ __launch_bounds__(256) void scanC_kernel(
    const unsigned* __restrict__ counts, const unsigned* __restrict__ blockSums,
    unsigned* __restrict__ offsets, unsigned* __restrict__ cursor)
{
    __shared__ unsigned sh[256];
    const int t = threadIdx.x;

    sh[t] = (t < blockIdx.x && t < NBLK) ? blockSums[t] : 0u;
    __syncthreads();
    for (int off = 128; off > 0; off >>= 1) {
        if (t < off) sh[t] += sh[t + off];
        __syncthreads();
    }
    unsigned blockPrefix = sh[0];
    __syncthreads();

    int i = blockIdx.x * 256 + t;
    unsigned c = (i < N_NODES) ? counts[i] : 0u;
    sh[t] = c;
    __syncthreads();
    for (int off = 1; off < 256; off <<= 1) {
        unsigned vv = (t >= off) ? sh[t - off] : 0u;
        __syncthreads();
        sh[t] += vv;
        __syncthreads();
    }
    unsigned ex = sh[t] - c + blockPrefix;
    if (i < N_NODES) { offsets[i] = ex; cursor[i] = ex; }
    if (i == 0) offsets[N_NODES] = N_EDGES;
}

// ---- Stage 3: per-edge destination slot ----
__global__ __launch_bounds__(256) void dst_kernel(
    const int* __restrict__ recv, unsigned* __restrict__ cursor,
    unsigned* __restrict__ dst)
{
    int i = blockIdx.x * 256 + threadIdx.x;
    if (i < N_EDGES / 4) {
        int4 r = reinterpret_cast<const int4*>(recv)[i];
        uint4 d;
        d.x = atomicAdd(&cursor[r.x], 1u);
        d.y = atomicAdd(&cursor[r.y], 1u);
        d.z = atomicAdd(&cursor[r.z], 1u);
        d.w = atomicAdd(&cursor[r.w], 1u);
        reinterpret_cast<uint4*>(dst)[i] = d;
    }
}

// ---- Stage 4: permuted copy f32 -> sorted bf16 rows ----
// 8 threads/row: thread reads 32B f32 (8 feats), writes 16B bf16 to sorted slot.
__global__ __launch_bounds__(256) void copy_kernel(
    const float* __restrict__ E, const unsigned* __restrict__ dst,
    unsigned* __restrict__ Es)   // packed bf16x2, row = 32 u32
{
    int t = blockIdx.x * 256 + threadIdx.x;   // < N_EDGES*8
    int edge = t >> 3;
    int c = t & 7;
    unsigned pos = dst[edge];
    const floatx4* E4 = reinterpret_cast<const floatx4*>(E);
    floatx4 a = __builtin_nontemporal_load(E4 + (size_t)edge * 16 + c * 2);
    floatx4 b = __builtin_nontemporal_load(E4 + (size_t)edge * 16 + c * 2 + 1);
    uint4 o;
    o.x = bf16rne(a.x) | (bf16rne(a.y) << 16);
    o.y = bf16rne(a.z) | (bf16rne(a.w) << 16);
    o.z = bf16rne(b.x) | (bf16rne(b.y) << 16);
    o.w = bf16rne(b.z) | (bf16rne(b.w) << 16);
    reinterpret_cast<uint4*>(Es)[(size_t)pos * 8 + c] = o;
}

// ---- Stage 5: fused segmented-mean (contiguous bf16 rows) + amortized MLP ----
// 512 blocks x 1024 thr = 8192 waves; wave g handles nodes {g + j*8192}.
// Mean: 8 rows per wave-load (lane l: row p+(l>>3), chunk c=l&7, 16B=8 bf16).
// MLP: one ds_read_b32 weight per K-step amortized over 7 nodes.
__global__ __launch_bounds__(1024, 8) void gather_mlp_kernel(
    const unsigned* __restrict__ Es, const unsigned* __restrict__ offsets,
    const float* __restrict__ v,
    const float* __restrict__ W0, const float* __restrict__ b0,
    const float* __restrict__ W1, const float* __restrict__ b1,
    const float* __restrict__ W2, const float* __restrict__ b2,
    float* __restrict__ out)
{
    __shared__ float sW0[128 * 64];
    __shared__ float sW1[64 * 64];
    __shared__ float sW2[64 * 64];
    __shared__ float sB[3 * 64];

    for (int i = threadIdx.x; i < 128 * 64; i += 1024) sW0[i] = W0[i];
    for (int i = threadIdx.x; i < 64 * 64; i += 1024) sW1[i] = W1[i];
    for (int i = threadIdx.x; i < 64 * 64; i += 1024) sW2[i] = W2[i];
    if (threadIdx.x < 192) {
        sB[threadIdx.x] = (threadIdx.x < 64)   ? b0[threadIdx.x]
                        : (threadIdx.x < 128)  ? b1[threadIdx.x - 64]
                                               : b2[threadIdx.x - 128];
    }
    __syncthreads();

    const int lane = threadIdx.x & 63;
    int g = (blockIdx.x * 1024 + threadIdx.x) >> 6;
    g = __builtin_amdgcn_readfirstlane(g);

    const int rg = lane >> 3;     // row-group 0..7
    const int ck = lane & 7;      // 16B chunk 0..7
    const uint4* Es4 = reinterpret_cast<const uint4*>(Es);

    float xa[NPWMAX], xv[NPWMAX];
    #pragma unroll
    for (int j = 0; j < NPWMAX; ++j) {
        int n = g + j * TOTAL_WAVES;
        xa[j] = 0.0f; xv[j] = 0.0f;
        if (n < N_NODES) {
            xv[j] = v[(size_t)n * H + lane];
            int beg = __builtin_amdgcn_readfirstlane((int)offsets[n]);
            int end = __builtin_amdgcn_readfirstlane((int)offsets[n + 1]);
            int cnt = end - beg;

            float f0 = 0.f, f1 = 0.f, f2 = 0.f, f3 = 0.f;
            float f4 = 0.f, f5 = 0.f, f6 = 0.f, f7 = 0.f;
            for (int p = beg; p < end; p += 8) {
                int r = p + rg;
                if (r < end) {
                    uint4 q = Es4[(size_t)r * 8 + ck];
                    f0 += bf16lo(q.x); f1 += bf16hi(q.x);
                    f2 += bf16lo(q.y); f3 += bf16hi(q.y);
                    f4 += bf16lo(q.z); f5 += bf16hi(q.z);
                    f6 += bf16lo(q.w); f7 += bf16hi(q.w);
                }
            }
            // reduce across 8 row-groups (lane bits 3,4,5)
            f0 += __shfl_xor(f0, 8);  f1 += __shfl_xor(f1, 8);
            f2 += __shfl_xor(f2, 8);  f3 += __shfl_xor(f3, 8);
            f4 += __shfl_xor(f4, 8);  f5 += __shfl_xor(f5, 8);
            f6 += __shfl_xor(f6, 8);  f7 += __shfl_xor(f7, 8);
            f0 += __shfl_xor(f0, 16); f1 += __shfl_xor(f1, 16);
            f2 += __shfl_xor(f2, 16); f3 += __shfl_xor(f3, 16);
            f4 += __shfl_xor(f4, 16); f5 += __shfl_xor(f5, 16);
            f6 += __shfl_xor(f6, 16); f7 += __shfl_xor(f7, 16);
            f0 += __shfl_xor(f0, 32); f1 += __shfl_xor(f1, 32);
            f2 += __shfl_xor(f2, 32); f3 += __shfl_xor(f3, 32);
            f4 += __shfl_xor(f4, 32); f5 += __shfl_xor(f5, 32);
            f6 += __shfl_xor(f6, 32); f7 += __shfl_xor(f7, 32);

            // redistribute: feature f=lane lives at slot f&7 of source lane f>>3
            int src = lane >> 3;
            float t0 = __shfl(f0, src), t1 = __shfl(f1, src);
            float t2 = __shfl(f2, src), t3 = __shfl(f3, src);
            float t4 = __shfl(f4, src), t5 = __shfl(f5, src);
            float t6 = __shfl(f6, src), t7 = __shfl(f7, src);
            float a01 = (lane & 1) ? t1 : t0;
            float a23 = (lane & 1) ? t3 : t2;
            float a45 = (lane & 1) ? t5 : t4;
            float a67 = (lane & 1) ? t7 : t6;
            float b03 = (lane & 2) ? a23 : a01;
            float b47 = (lane & 2) ? a67 : a45;
            float sel = (lane & 4) ? b47 : b03;

            float invc = (cnt > 0) ? 1.0f / (float)cnt : 0.0f;
            xa[j] = sel * invc;
        }
    }

    // ---- MLP: 1 LDS weight read per K-step, shared by 7 nodes ----
    float acc[NPWMAX];
    #pragma unroll
    for (int j = 0; j < NPWMAX; ++j) acc[j] = sB[lane];
    #pragma unroll 8
    for (int i = 0; i < 64; ++i) {
        float w = sW0[i * 64 + lane];
        #pragma unroll
        for (int j = 0; j < NPWMAX; ++j) acc[j] = fmaf(readlane_f(xa[j], i), w, acc[j]);
    }
    #pragma unroll 8
    for (int i = 0; i < 64; ++i) {
        float w = sW0[(64 + i) * 64 + lane];
        #pragma unroll
        for (int j = 0; j < NPWMAX; ++j) acc[j] = fmaf(readlane_f(xv[j], i), w, acc[j]);
    }
    float y[NPWMAX];
    #pragma unroll
    for (int j = 0; j < NPWMAX; ++j) y[j] = fmaxf(acc[j], 0.0f);

    #pragma unroll
    for (int j = 0; j < NPWMAX; ++j) acc[j] = sB[64 + lane];
    #pragma unroll 8
    for (int i = 0; i < 64; ++i) {
        float w = sW1[i * 64 + lane];
        #pragma unroll
        for (int j = 0; j < NPWMAX; ++j) acc[j] = fmaf(readlane_f(y[j], i), w, acc[j]);
    }
    float z[NPWMAX];
    #pragma unroll
    for (int j = 0; j < NPWMAX; ++j) z[j] = fmaxf(acc[j], 0.0f);

    #pragma unroll
    for (int j = 0; j < NPWMAX; ++j) acc[j] = sB[128 + lane];
    #pragma unroll 8
    for (int i = 0; i < 64; ++i) {
        float w = sW2[i * 64 + lane];
        #pragma unroll
        for (int j = 0; j < NPWMAX; ++j) acc[j] = fmaf(readlane_f(z[j], i), w, acc[j]);
    }

    #pragma unroll
    for (int j = 0; j < NPWMAX; ++j) {
        int n = g + j * TOTAL_WAVES;
        if (n < N_NODES) out[(size_t)n * H + lane] = acc[j];
    }
}

extern "C" void kernel_launch(void* const* d_in, const int* in_sizes, int n_in,
                              void* d_out, int out_size, void* d_ws, size_t ws_size,
                              hipStream_t stream)
{
    const float* v  = (const float*)d_in[0];
    const int*   ei = (const int*)d_in[1];     // [2, 800000]; row 1 = receiver
    const float* e  = (const float*)d_in[2];
    const float* W0 = (const float*)d_in[3];
    const float* b0 = (const float*)d_in[4];
    const float* W1 = (const float*)d_in[5];
    const float* b1 = (const float*)d_in[6];
    const float* W2 = (const float*)d_in[7];
    const float* b2 = (const float*)d_in[8];
    float* out = (float*)d_out;

    // workspace layout (u32 elements)
    unsigned* W = (unsigned*)d_ws;
    unsigned* counts    = W;                    // [0, 50176)
    unsigned* offsets   = W + 50176;            // 50001 (+pad)
    unsigned* cursor    = W + 100352;           // 50000 (+pad)
    unsigned* blockSums = W + 150528;           // 196 (+pad)
    unsigned* dst       = W + 150784;           // 800000
    unsigned* Es        = W + 950784;           // 800000 rows * 32 u32 = 25.6M u32
    const int* recv = ei + N_EDGES;

    (void)hipMemsetAsync(counts, 0, 50176 * sizeof(unsigned), stream);

    hist_kernel<<<(N_EDGES / 4 + 255) / 256, 256, 0, stream>>>(recv, counts);
    scanA_kernel<<<NBLK, 256, 0, stream>>>(counts, blockSums);
    scanC_kernel<<<NBLK, 256, 0, stream>>>(counts, blockSums, offsets, cursor);
    dst_kernel<<<(N_EDGES / 4 + 255) / 256, 256, 0, stream>>>(recv, cursor, dst);
    copy_kernel<<<(N_EDGES * 8) / 256, 256, 0, stream>>>(e, dst, Es);
    gather_mlp_kernel<<<512, 1024, 0, stream>>>(
        Es, offsets, v, W0, b0, W1, b1, W2, b2, out);
}